// Round 7
// baseline (187.605 us; speedup 1.0000x reference)
//
#include <hip/hip_runtime.h>
#include <math.h>

// GATConv (PyG 1.3.2), H=1, IN=C=128. memset + 2 dispatches:
//  memset: gcur[N] = 0
//  k2 gemm_scatter: heterogeneous grid — blocks [0,sb): DIRECT per-node CSR scatter
//                   (1 pass, no LDS: pos=atomicAdd(gcur[dst]); recs[dst*64+pos]=src);
//                   blocks [sb,sb+gb): MFMA bf16 gemm, W^T built in-LDS,
//                   hb via LDS-bounce coalesced dwordx4.
//  k3 aggregate: PURE gather — no sort, no LDS, no barriers. Per node: read 256B
//                recs row (broadcast), p=exp(leaky(ad+as)) in-loop (as_ loads issued
//                before row loads), 16-deep 256B-row gather, normalize, store.
// recs layout: per-node 64-slot rows (256 B aligned), 12.8 MB. Max degree safety:
// Poisson(mean 17) -> P(deg>63) ~ 1e-17 per node; drop-guard same as old CAP.

constexpr int CH = 128;
constexpr int BNODES = 64;     // dst nodes per k3 block
constexpr int DCAP = 64;       // slots per node (256 B row)
constexpr int SCHUNK = 4096;   // edges per scatter block
constexpr int WTS = 136;       // padded row stride in bf16 (16B-aligned)

typedef __attribute__((ext_vector_type(8))) short bf16x8;
typedef __attribute__((ext_vector_type(4))) float f32x4;

static __device__ __forceinline__ unsigned short f2bf(float f) {
    unsigned u = __float_as_uint(f);
    unsigned r = (u + 0x7fffu + ((u >> 16) & 1u)) >> 16;   // RNE
    return (unsigned short)r;
}

// Heterogeneous: blocks [0,sb) scatter, [sb,sb+gb) gemm (2x64-row tiles). 256 thr.
__global__ __launch_bounds__(256) void gemm_scatter_kernel(const float* __restrict__ x,
                                                           const float* __restrict__ W,
                                                           const float* __restrict__ att,
                                                           unsigned short* __restrict__ hb,
                                                           float* __restrict__ ad,
                                                           float* __restrict__ as_,
                                                           const int* __restrict__ src,
                                                           const int* __restrict__ dst,
                                                           int* __restrict__ gcur,
                                                           unsigned* __restrict__ recs,
                                                           int n, int etot, int sb) {
    __shared__ alignas(16) unsigned char smem[52224];   // Wl 34816 + Xs 17408
    const int tid = threadIdx.x;

    if ((int)blockIdx.x >= sb) {
        // ------- GEMM branch: 128 rows = 2 x-tiles; Wl built in-LDS from W -------
        unsigned short* Wl = (unsigned short*)smem;                  // 34816 B
        unsigned short* Xs = (unsigned short*)(smem + 34816);        // 64 x WTS bf16
        unsigned short* outb = Xs;                                   // reused as out-bounce
        {
            const int kb4 = tid >> 3;       // 0..31
            const int nb16 = tid & 7;       // 0..7
            const float* wp = W + (size_t)(kb4 * 4) * CH + nb16 * 16;
            const float4 r0a = *(const float4*)(wp + 0);
            const float4 r0b = *(const float4*)(wp + 4);
            const float4 r0c = *(const float4*)(wp + 8);
            const float4 r0d = *(const float4*)(wp + 12);
            const float4 r1a = *(const float4*)(wp + CH + 0);
            const float4 r1b = *(const float4*)(wp + CH + 4);
            const float4 r1c = *(const float4*)(wp + CH + 8);
            const float4 r1d = *(const float4*)(wp + CH + 12);
            const float4 r2a = *(const float4*)(wp + 2 * CH + 0);
            const float4 r2b = *(const float4*)(wp + 2 * CH + 4);
            const float4 r2c = *(const float4*)(wp + 2 * CH + 8);
            const float4 r2d = *(const float4*)(wp + 2 * CH + 12);
            const float4 r3a = *(const float4*)(wp + 3 * CH + 0);
            const float4 r3b = *(const float4*)(wp + 3 * CH + 4);
            const float4 r3c = *(const float4*)(wp + 3 * CH + 8);
            const float4 r3d = *(const float4*)(wp + 3 * CH + 12);
            unsigned short* wl = Wl + (nb16 * 16) * WTS + kb4 * 4;
            #define WRC(c, f0, f1, f2, f3) { ushort4 t_;                         \
                t_.x = f2bf(f0); t_.y = f2bf(f1); t_.z = f2bf(f2); t_.w = f2bf(f3); \
                *(ushort4*)&wl[(c) * WTS] = t_; }
            WRC(0,  r0a.x, r1a.x, r2a.x, r3a.x)
            WRC(1,  r0a.y, r1a.y, r2a.y, r3a.y)
            WRC(2,  r0a.z, r1a.z, r2a.z, r3a.z)
            WRC(3,  r0a.w, r1a.w, r2a.w, r3a.w)
            WRC(4,  r0b.x, r1b.x, r2b.x, r3b.x)
            WRC(5,  r0b.y, r1b.y, r2b.y, r3b.y)
            WRC(6,  r0b.z, r1b.z, r2b.z, r3b.z)
            WRC(7,  r0b.w, r1b.w, r2b.w, r3b.w)
            WRC(8,  r0c.x, r1c.x, r2c.x, r3c.x)
            WRC(9,  r0c.y, r1c.y, r2c.y, r3c.y)
            WRC(10, r0c.z, r1c.z, r2c.z, r3c.z)
            WRC(11, r0c.w, r1c.w, r2c.w, r3c.w)
            WRC(12, r0d.x, r1d.x, r2d.x, r3d.x)
            WRC(13, r0d.y, r1d.y, r2d.y, r3d.y)
            WRC(14, r0d.z, r1d.z, r2d.z, r3d.z)
            WRC(15, r0d.w, r1d.w, r2d.w, r3d.w)
            #undef WRC
        }

        const int lane = tid & 63, wave = tid >> 6;
        const int m = lane & 15, quad = lane >> 4;
        const int tbase = ((int)blockIdx.x - sb) * 128;
        const int srow = tid >> 2, sseg = tid & 3;

        #pragma unroll 1
        for (int half = 0; half < 2; ++half) {
            __syncthreads();   // protect Xs (and cover Wl build / prev store bounce)
            {
                const int grow = min(tbase + half * 64 + srow, n - 1);
                const float* gx = x + (size_t)grow * CH;
                unsigned short* xd = &Xs[srow * WTS];
                #pragma unroll
                for (int i = 0; i < 8; ++i) {
                    const int c = sseg * 4 + i * 16;
                    const float4 u = *(const float4*)&gx[c];
                    ushort4 hs;
                    hs.x = f2bf(u.x); hs.y = f2bf(u.y); hs.z = f2bf(u.z); hs.w = f2bf(u.w);
                    *(ushort4*)&xd[c] = hs;
                }
            }
            __syncthreads();

            const int row0 = tbase + half * 64 + wave * 16;
            f32x4 acc[8] = {};
            #pragma unroll
            for (int t = 0; t < 4; ++t) {
                const int kb = t * 32 + quad * 8;
                const bf16x8 afr = *(const bf16x8*)&Xs[(wave * 16 + m) * WTS + kb];
                #pragma unroll
                for (int nt = 0; nt < 8; ++nt) {
                    const bf16x8 bfr = *(const bf16x8*)&Wl[(nt * 16 + m) * WTS + kb];
                    acc[nt] = __builtin_amdgcn_mfma_f32_16x16x32_bf16(afr, bfr, acc[nt], 0, 0, 0);
                }
            }

            // ---- alpha partials (register-only) ----
            const int rbase = row0 + quad * 4;
            float pd[4] = {}, ps[4] = {};
            #pragma unroll
            for (int nt = 0; nt < 8; ++nt) {
                const int col = nt * 16 + m;
                const float atd = att[col], ats = att[CH + col];
                #pragma unroll
                for (int r = 0; r < 4; ++r) {
                    pd[r] = fmaf(acc[nt][r], atd, pd[r]);
                    ps[r] = fmaf(acc[nt][r], ats, ps[r]);
                }
            }
            #pragma unroll
            for (int r = 0; r < 4; ++r) {
                #pragma unroll
                for (int off = 8; off >= 1; off >>= 1) {
                    pd[r] += __shfl_xor(pd[r], off, 64);
                    ps[r] += __shfl_xor(ps[r], off, 64);
                }
                const int rr = rbase + r;
                if (m == 0 && rr < n) { ad[rr] = pd[r]; as_[rr] = ps[r]; }
            }

            // ---- hb store via LDS bounce: bf16 tile then coalesced dwordx4 ----
            __syncthreads();   // all waves done reading Xs as A-fragments
            {
                const int lrow = wave * 16 + quad * 4;
                #pragma unroll
                for (int nt = 0; nt < 8; ++nt) {
                    const int col = nt * 16 + m;
                    #pragma unroll
                    for (int r = 0; r < 4; ++r)
                        outb[(lrow + r) * CH + col] = f2bf(acc[nt][r]);
                }
            }
            __syncthreads();
            {
                const int lr = tid >> 4, seg = tid & 15;
                #pragma unroll
                for (int pass = 0; pass < 4; ++pass) {
                    const int row = pass * 16 + lr;
                    const int grow = tbase + half * 64 + row;
                    if (grow < n) {
                        const uint4 v = *(const uint4*)&outb[row * CH + seg * 8];
                        *(uint4*)&hb[(size_t)grow * CH + seg * 8] = v;
                    }
                }
            }
        }
    } else {
        // ------- SCATTER branch: direct per-node CSR, 1 pass, no LDS -------
        const int e0 = (int)blockIdx.x * SCHUNK;
        for (int i = tid * 4; i < SCHUNK; i += 1024) {
            const int e = e0 + i;
            if (e + 3 < etot) {
                const int4 s4 = *(const int4*)&src[e];
                const int4 d4 = *(const int4*)&dst[e];
                const int p0 = atomicAdd(&gcur[d4.x], 1);
                if (p0 < DCAP) recs[(size_t)d4.x * DCAP + p0] = (unsigned)s4.x;
                const int p1 = atomicAdd(&gcur[d4.y], 1);
                if (p1 < DCAP) recs[(size_t)d4.y * DCAP + p1] = (unsigned)s4.y;
                const int p2 = atomicAdd(&gcur[d4.z], 1);
                if (p2 < DCAP) recs[(size_t)d4.z * DCAP + p2] = (unsigned)s4.z;
                const int p3 = atomicAdd(&gcur[d4.w], 1);
                if (p3 < DCAP) recs[(size_t)d4.w * DCAP + p3] = (unsigned)s4.w;
            } else {
                #pragma unroll
                for (int k = 0; k < 4; ++k) {
                    const int ek = e + k;
                    if (ek < etot) {
                        const int d = dst[ek];
                        const int pos = atomicAdd(&gcur[d], 1);
                        if (pos < DCAP) recs[(size_t)d * DCAP + pos] = (unsigned)src[ek];
                    }
                }
            }
        }
    }
}

// One 512-thread block per 64 nodes. Pure gather: no LDS, no barriers.
// Per wave, per node: broadcast recs row + as_ loads (issued first), then 16
// 256B-row loads in flight, p=exp(leaky) masked by validity, fma accumulate.
__global__ __launch_bounds__(512) void aggregate_kernel(const unsigned char* __restrict__ hwb,
                                                        const float* __restrict__ ad,
                                                        const float* __restrict__ as_,
                                                        const int* __restrict__ gcur,
                                                        const unsigned* __restrict__ recs,
                                                        const float* __restrict__ bias,
                                                        float* __restrict__ out, int n) {
    const int b = blockIdx.x;
    const int tid = threadIdx.x, lane = tid & 63, wid = tid >> 6;
    const unsigned lane4 = (unsigned)lane * 4u;

    for (int ln = wid; ln < BNODES; ln += 8) {
        const int node = b * BNODES + ln;
        if (node >= n) break;
        int cnt = gcur[node]; if (cnt > DCAP) cnt = DCAP;
        const float adv = ad[node];
        const unsigned* er = recs + (size_t)node * DCAP;

        float ssum = 0.f, acc0 = 0.f, acc1 = 0.f;
        for (int g = 0; g < cnt; g += 16) {
            const uint4 r0 = *(const uint4*)&er[g];
            const uint4 r1 = *(const uint4*)&er[g + 4];
            const uint4 r2 = *(const uint4*)&er[g + 8];
            const uint4 r3 = *(const uint4*)&er[g + 12];
            unsigned sid[16];
            sid[0]  = (g + 0  < cnt) ? r0.x : 0u;
            sid[1]  = (g + 1  < cnt) ? r0.y : 0u;
            sid[2]  = (g + 2  < cnt) ? r0.z : 0u;
            sid[3]  = (g + 3  < cnt) ? r0.w : 0u;
            sid[4]  = (g + 4  < cnt) ? r1.x : 0u;
            sid[5]  = (g + 5  < cnt) ? r1.y : 0u;
            sid[6]  = (g + 6  < cnt) ? r1.z : 0u;
            sid[7]  = (g + 7  < cnt) ? r1.w : 0u;
            sid[8]  = (g + 8  < cnt) ? r2.x : 0u;
            sid[9]  = (g + 9  < cnt) ? r2.y : 0u;
            sid[10] = (g + 10 < cnt) ? r2.z : 0u;
            sid[11] = (g + 11 < cnt) ? r2.w : 0u;
            sid[12] = (g + 12 < cnt) ? r3.x : 0u;
            sid[13] = (g + 13 < cnt) ? r3.y : 0u;
            sid[14] = (g + 14 < cnt) ? r3.z : 0u;
            sid[15] = (g + 15 < cnt) ? r3.w : 0u;
            float av[16];
            #pragma unroll
            for (int t = 0; t < 16; ++t) av[t] = as_[sid[t]];   // broadcast, issued first
            unsigned gv[16];
            #pragma unroll
            for (int t = 0; t < 16; ++t)
                gv[t] = *(const unsigned*)(hwb + ((size_t)sid[t] << 8) + lane4);
            #pragma unroll
            for (int t = 0; t < 16; ++t) {
                float a = adv + av[t];
                a = (a >= 0.f) ? a : 0.2f * a;
                const float p = (g + t < cnt) ? __expf(a) : 0.f;
                ssum += p;
                acc0 = fmaf(p, __uint_as_float((gv[t] & 0xffffu) << 16), acc0);
                acc1 = fmaf(p, __uint_as_float(gv[t] & 0xffff0000u), acc1);
            }
        }
        const float inv = 1.f / (ssum + 1e-16f);
        const float2 bv = *(const float2*)&bias[lane * 2];
        float2 o;
        o.x = fmaf(acc0, inv, bv.x);
        o.y = fmaf(acc1, inv, bv.y);
        *(float2*)&out[(size_t)node * CH + lane * 2] = o;
    }
}

extern "C" void kernel_launch(void* const* d_in, const int* in_sizes, int n_in,
                              void* d_out, int out_size, void* d_ws, size_t ws_size,
                              hipStream_t stream) {
    const float* x    = (const float*)d_in[0];
    const int*   ei   = (const int*)d_in[1];
    const float* W    = (const float*)d_in[2];
    const float* att  = (const float*)d_in[3];
    const float* bias = (const float*)d_in[4];
    float* out = (float*)d_out;

    const int N_   = in_sizes[0] / CH;   // 50000
    const int Etot = in_sizes[1] / 2;    // 850000
    const int* src = ei;
    const int* dst = ei + Etot;
    const int nb = (N_ + BNODES - 1) / BNODES;        // 782 aggregate blocks
    const int gb = (N_ + 127) / 128;                  // 391 gemm blocks
    const int sb = (Etot + SCHUNK - 1) / SCHUNK;      // 208 scatter blocks

    char* ws = (char*)d_ws;
    size_t off = 0;
    auto alloc = [&](size_t bytes) -> void* {
        void* p = ws + off;
        off = (off + bytes + 255) & ~(size_t)255;
        return p;
    };
    unsigned short* hb = (unsigned short*)alloc((size_t)N_ * CH * sizeof(unsigned short));
    float* ad      = (float*)alloc((size_t)N_ * sizeof(float));
    float* as_     = (float*)alloc((size_t)N_ * sizeof(float));
    int*   gcur    = (int*)  alloc((size_t)N_ * sizeof(int));
    unsigned* recs = (unsigned*)alloc((size_t)N_ * DCAP * sizeof(unsigned));
    (void)ws_size; (void)n_in; (void)out_size;

    hipMemsetAsync(gcur, 0, (size_t)N_ * sizeof(int), stream);
    gemm_scatter_kernel<<<sb + gb, 256, 0, stream>>>(x, W, att, hb, ad, as_,
                                                     src, dst, gcur, recs, N_, Etot, sb);
    aggregate_kernel<<<nb, 512, 0, stream>>>((const unsigned char*)hb, ad, as_, gcur, recs, bias, out, N_);
}

// Round 8
// 135.385 us; speedup vs baseline: 1.3857x; 1.3857x over previous
//
#include <hip/hip_runtime.h>
#include <math.h>

// GATConv (PyG 1.3.2), H=1, IN=C=128. memset + 2 dispatches:
//  memset: gcur = 0
//  k2 gemm_scatter: heterogeneous grid — blocks [0,sb): bucket-scatter (LDS 3-pass,
//                   int4 edge reads); blocks [sb,sb+gb): MFMA bf16 gemm, W^T in-LDS,
//                   hb via LDS-bounce coalesced dwordx4.
//  k3 aggregate: per-bucket LDS counting sort (proven round-0 structure) at
//                BNODES=32 / 256-thr blocks: ~13KB LDS -> 8 blocks/CU (32 waves/CU,
//                2x round-0 occupancy & in-flight gather loads), finer tail.

constexpr int CH = 128;
constexpr int BNODES = 32;     // dst nodes per bucket
constexpr int CAP = 1024;      // max edges per bucket (avg ~544)
constexpr int SCAP = 1536;     // CAP + 32*15 pad headroom (1504 max)
constexpr int NBMAX = 2048;    // supports N <= 65536 at BNODES=32
constexpr int SCHUNK = 4096;   // edges per scatter block
constexpr int WTS = 136;       // padded row stride in bf16 (16B-aligned)
constexpr unsigned SENT = 0xFFFFFFFFu;

typedef __attribute__((ext_vector_type(8))) short bf16x8;
typedef __attribute__((ext_vector_type(4))) float f32x4;

static __device__ __forceinline__ unsigned short f2bf(float f) {
    unsigned u = __float_as_uint(f);
    unsigned r = (u + 0x7fffu + ((u >> 16) & 1u)) >> 16;   // RNE
    return (unsigned short)r;
}

// Heterogeneous: blocks [0,sb) scatter, [sb,sb+gb) gemm (2x64-row tiles). 256 thr.
__global__ __launch_bounds__(256) void gemm_scatter_kernel(const float* __restrict__ x,
                                                           const float* __restrict__ W,
                                                           const float* __restrict__ att,
                                                           unsigned short* __restrict__ hb,
                                                           float* __restrict__ ad,
                                                           float* __restrict__ as_,
                                                           const int* __restrict__ src,
                                                           const int* __restrict__ dst,
                                                           int* __restrict__ gcur,
                                                           unsigned* __restrict__ recs,
                                                           int n, int etot, int nb, int sb) {
    __shared__ alignas(16) unsigned char smem[52224];   // Wl 34816 + Xs 17408
    const int tid = threadIdx.x;

    if ((int)blockIdx.x >= sb) {
        // ------- GEMM branch: 128 rows = 2 x-tiles; Wl built in-LDS from W -------
        unsigned short* Wl = (unsigned short*)smem;                  // 34816 B
        unsigned short* Xs = (unsigned short*)(smem + 34816);        // 64 x WTS bf16
        unsigned short* outb = Xs;                                   // reused as out-bounce
        {
            const int kb4 = tid >> 3;       // 0..31
            const int nb16 = tid & 7;       // 0..7
            const float* wp = W + (size_t)(kb4 * 4) * CH + nb16 * 16;
            const float4 r0a = *(const float4*)(wp + 0);
            const float4 r0b = *(const float4*)(wp + 4);
            const float4 r0c = *(const float4*)(wp + 8);
            const float4 r0d = *(const float4*)(wp + 12);
            const float4 r1a = *(const float4*)(wp + CH + 0);
            const float4 r1b = *(const float4*)(wp + CH + 4);
            const float4 r1c = *(const float4*)(wp + CH + 8);
            const float4 r1d = *(const float4*)(wp + CH + 12);
            const float4 r2a = *(const float4*)(wp + 2 * CH + 0);
            const float4 r2b = *(const float4*)(wp + 2 * CH + 4);
            const float4 r2c = *(const float4*)(wp + 2 * CH + 8);
            const float4 r2d = *(const float4*)(wp + 2 * CH + 12);
            const float4 r3a = *(const float4*)(wp + 3 * CH + 0);
            const float4 r3b = *(const float4*)(wp + 3 * CH + 4);
            const float4 r3c = *(const float4*)(wp + 3 * CH + 8);
            const float4 r3d = *(const float4*)(wp + 3 * CH + 12);
            unsigned short* wl = Wl + (nb16 * 16) * WTS + kb4 * 4;
            #define WRC(c, f0, f1, f2, f3) { ushort4 t_;                         \
                t_.x = f2bf(f0); t_.y = f2bf(f1); t_.z = f2bf(f2); t_.w = f2bf(f3); \
                *(ushort4*)&wl[(c) * WTS] = t_; }
            WRC(0,  r0a.x, r1a.x, r2a.x, r3a.x)
            WRC(1,  r0a.y, r1a.y, r2a.y, r3a.y)
            WRC(2,  r0a.z, r1a.z, r2a.z, r3a.z)
            WRC(3,  r0a.w, r1a.w, r2a.w, r3a.w)
            WRC(4,  r0b.x, r1b.x, r2b.x, r3b.x)
            WRC(5,  r0b.y, r1b.y, r2b.y, r3b.y)
            WRC(6,  r0b.z, r1b.z, r2b.z, r3b.z)
            WRC(7,  r0b.w, r1b.w, r2b.w, r3b.w)
            WRC(8,  r0c.x, r1c.x, r2c.x, r3c.x)
            WRC(9,  r0c.y, r1c.y, r2c.y, r3c.y)
            WRC(10, r0c.z, r1c.z, r2c.z, r3c.z)
            WRC(11, r0c.w, r1c.w, r2c.w, r3c.w)
            WRC(12, r0d.x, r1d.x, r2d.x, r3d.x)
            WRC(13, r0d.y, r1d.y, r2d.y, r3d.y)
            WRC(14, r0d.z, r1d.z, r2d.z, r3d.z)
            WRC(15, r0d.w, r1d.w, r2d.w, r3d.w)
            #undef WRC
        }

        const int lane = tid & 63, wave = tid >> 6;
        const int m = lane & 15, quad = lane >> 4;
        const int tbase = ((int)blockIdx.x - sb) * 128;
        const int srow = tid >> 2, sseg = tid & 3;

        #pragma unroll 1
        for (int half = 0; half < 2; ++half) {
            __syncthreads();   // protect Xs (and cover Wl build / prev store bounce)
            {
                const int grow = min(tbase + half * 64 + srow, n - 1);
                const float* gx = x + (size_t)grow * CH;
                unsigned short* xd = &Xs[srow * WTS];
                #pragma unroll
                for (int i = 0; i < 8; ++i) {
                    const int c = sseg * 4 + i * 16;
                    const float4 u = *(const float4*)&gx[c];
                    ushort4 hs;
                    hs.x = f2bf(u.x); hs.y = f2bf(u.y); hs.z = f2bf(u.z); hs.w = f2bf(u.w);
                    *(ushort4*)&xd[c] = hs;
                }
            }
            __syncthreads();

            const int row0 = tbase + half * 64 + wave * 16;
            f32x4 acc[8] = {};
            #pragma unroll
            for (int t = 0; t < 4; ++t) {
                const int kb = t * 32 + quad * 8;
                const bf16x8 afr = *(const bf16x8*)&Xs[(wave * 16 + m) * WTS + kb];
                #pragma unroll
                for (int nt = 0; nt < 8; ++nt) {
                    const bf16x8 bfr = *(const bf16x8*)&Wl[(nt * 16 + m) * WTS + kb];
                    acc[nt] = __builtin_amdgcn_mfma_f32_16x16x32_bf16(afr, bfr, acc[nt], 0, 0, 0);
                }
            }

            // ---- alpha partials (register-only) ----
            const int rbase = row0 + quad * 4;
            float pd[4] = {}, ps[4] = {};
            #pragma unroll
            for (int nt = 0; nt < 8; ++nt) {
                const int col = nt * 16 + m;
                const float atd = att[col], ats = att[CH + col];
                #pragma unroll
                for (int r = 0; r < 4; ++r) {
                    pd[r] = fmaf(acc[nt][r], atd, pd[r]);
                    ps[r] = fmaf(acc[nt][r], ats, ps[r]);
                }
            }
            #pragma unroll
            for (int r = 0; r < 4; ++r) {
                #pragma unroll
                for (int off = 8; off >= 1; off >>= 1) {
                    pd[r] += __shfl_xor(pd[r], off, 64);
                    ps[r] += __shfl_xor(ps[r], off, 64);
                }
                const int rr = rbase + r;
                if (m == 0 && rr < n) { ad[rr] = pd[r]; as_[rr] = ps[r]; }
            }

            // ---- hb store via LDS bounce: bf16 tile then coalesced dwordx4 ----
            __syncthreads();   // all waves done reading Xs as A-fragments
            {
                const int lrow = wave * 16 + quad * 4;
                #pragma unroll
                for (int nt = 0; nt < 8; ++nt) {
                    const int col = nt * 16 + m;
                    #pragma unroll
                    for (int r = 0; r < 4; ++r)
                        outb[(lrow + r) * CH + col] = f2bf(acc[nt][r]);
                }
            }
            __syncthreads();
            {
                const int lr = tid >> 4, seg = tid & 15;
                #pragma unroll
                for (int pass = 0; pass < 4; ++pass) {
                    const int row = pass * 16 + lr;
                    const int grow = tbase + half * 64 + row;
                    if (grow < n) {
                        const uint4 v = *(const uint4*)&outb[row * CH + seg * 8];
                        *(uint4*)&hb[(size_t)grow * CH + seg * 8] = v;
                    }
                }
            }
        }
    } else {
        // ------- SCATTER branch: bin SCHUNK edges into buckets (LDS stash) -------
        int* hist = (int*)smem;                       // 8192 B
        int* cur = hist + NBMAX;                      // 8192 B
        unsigned* rbuf = (unsigned*)(cur + NBMAX);    // 16384 B
        const int e0 = (int)blockIdx.x * SCHUNK;
        for (int t = tid; t < nb; t += 256) hist[t] = 0;
        __syncthreads();
        for (int i = tid * 4; i < SCHUNK; i += 1024) {
            const int e = e0 + i;
            if (e + 3 < etot) {
                const int4 s4 = *(const int4*)&src[e];
                const int4 d4 = *(const int4*)&dst[e];
                uint4 rb;
                rb.x = ((unsigned)d4.x << 16) | (unsigned)s4.x;
                rb.y = ((unsigned)d4.y << 16) | (unsigned)s4.y;
                rb.z = ((unsigned)d4.z << 16) | (unsigned)s4.z;
                rb.w = ((unsigned)d4.w << 16) | (unsigned)s4.w;
                *(uint4*)&rbuf[i] = rb;
                atomicAdd(&hist[d4.x >> 5], 1);
                atomicAdd(&hist[d4.y >> 5], 1);
                atomicAdd(&hist[d4.z >> 5], 1);
                atomicAdd(&hist[d4.w >> 5], 1);
            } else {
                #pragma unroll
                for (int k = 0; k < 4; ++k) {
                    const int ek = e + k;
                    if (ek < etot) {
                        const int d = dst[ek];
                        rbuf[i + k] = ((unsigned)d << 16) | (unsigned)src[ek];
                        atomicAdd(&hist[d >> 5], 1);
                    }
                }
            }
        }
        __syncthreads();
        for (int t = tid; t < nb; t += 256) {
            const int h = hist[t];
            cur[t] = h ? atomicAdd(&gcur[t], h) : 0;   // reserve contiguous range
        }
        __syncthreads();
        for (int i = tid * 4; i < SCHUNK; i += 1024) {
            const int e = e0 + i;
            const uint4 rb = *(const uint4*)&rbuf[i];
            #pragma unroll
            for (int k = 0; k < 4; ++k) {
                if (e + k < etot) {
                    const unsigned r = (k == 0) ? rb.x : (k == 1) ? rb.y : (k == 2) ? rb.z : rb.w;
                    const int d = (int)(r >> 16);
                    const int b = d >> 5;
                    const int pos = atomicAdd(&cur[b], 1);
                    if (pos < CAP)
                        recs[(size_t)b * CAP + pos] = ((unsigned)(d & 31) << 16) | (r & 0xffffu);
                }
            }
        }
    }
}

// One 256-thread block per 32-node bucket (8 blocks/CU -> ~32 waves/CU).
// stash+hist -> scan(x16 pad) -> sort -> p=exp(leaky) -> per-wave 16-deep gather.
__global__ __launch_bounds__(256) void aggregate_kernel(const unsigned char* __restrict__ hwb,
                                                        const float* __restrict__ ad,
                                                        const float* __restrict__ as_,
                                                        const int* __restrict__ gcur,
                                                        const unsigned* __restrict__ recs,
                                                        const float* __restrict__ bias,
                                                        float* __restrict__ out, int n) {
    __shared__ alignas(16) unsigned sorted[SCAP];
    __shared__ alignas(16) float alphas[SCAP];
    __shared__ float adl[BNODES];
    __shared__ int cnt[BNODES], ofs[BNODES], cur[BNODES];
    __shared__ int nEp_s;
    const int b = blockIdx.x;
    const int tid = threadIdx.x, lane = tid & 63, wid = tid >> 6;
    const unsigned* br = recs + (size_t)b * CAP;
    int nE = gcur[b]; if (nE > CAP) nE = CAP;
    unsigned* stash = (unsigned*)alphas;

    if (tid < BNODES) {
        cnt[tid] = 0;
        const int node = b * BNODES + tid;
        adl[tid] = (node < n) ? ad[node] : 0.f;
    }
    __syncthreads();
    for (int i = tid; i < nE; i += 256) {
        const unsigned r = br[i];
        stash[i] = r;
        atomicAdd(&cnt[r >> 16], 1);
    }
    __syncthreads();
    if (wid == 0) {                       // exclusive scan of x16-rounded counts (32)
        const int c = (lane < BNODES) ? cnt[lane] : 0;
        const int cr = (c + 15) & ~15;
        int v = cr;
        #pragma unroll
        for (int off = 1; off < 32; off <<= 1) {
            const int u = __shfl_up(v, (unsigned)off, 64);
            if (lane >= off) v += u;
        }
        if (lane < BNODES) {
            ofs[lane] = v - cr;
            cur[lane] = v - cr;
            if (lane == BNODES - 1) nEp_s = v;
        }
    }
    __syncthreads();
    const int nEp = nEp_s;
    for (int i = tid; i < nEp; i += 256) sorted[i] = SENT;
    __syncthreads();
    for (int i = tid; i < nE; i += 256) {
        const unsigned r = stash[i];
        const int pos = atomicAdd(&cur[r >> 16], 1);
        sorted[pos] = r;
    }
    __syncthreads();
    // p = exp(leaky_relu(ad[dst]+as[src])); rec -> h byte-offset (src*256); pad p=0.
    for (int i = tid; i < nEp; i += 256) {   // overwrites stash
        const unsigned r = sorted[i];
        float p = 0.f;
        unsigned so = 0u;
        if (r != SENT) {
            float a = adl[r >> 16] + as_[r & 0xffffu];
            a = (a >= 0.f) ? a : 0.2f * a;
            p = __expf(a);
            so = (r & 0xffffu) << 8;
        }
        alphas[i] = p;
        sorted[i] = so;
    }
    __syncthreads();

    const unsigned lane4 = (unsigned)lane * 4u;
    for (int ln = wid; ln < BNODES; ln += 4) {
        const int node = b * BNODES + ln;
        if (node >= n) break;
        const int start = ofs[ln];
        const int endp = start + ((cnt[ln] + 15) & ~15);

        float ssum = 0.f, acc0 = 0.f, acc1 = 0.f;
        for (int e = start; e < endp; e += 16) {
            const uint4 s0 = *(const uint4*)&sorted[e];
            const uint4 s1 = *(const uint4*)&sorted[e + 4];
            const uint4 s2 = *(const uint4*)&sorted[e + 8];
            const uint4 s3 = *(const uint4*)&sorted[e + 12];
            const float4 p0 = *(const float4*)&alphas[e];
            const float4 p1 = *(const float4*)&alphas[e + 4];
            const float4 p2 = *(const float4*)&alphas[e + 8];
            const float4 p3 = *(const float4*)&alphas[e + 12];
            unsigned g[16];
            g[0]  = *(const unsigned*)(hwb + (s0.x + lane4));
            g[1]  = *(const unsigned*)(hwb + (s0.y + lane4));
            g[2]  = *(const unsigned*)(hwb + (s0.z + lane4));
            g[3]  = *(const unsigned*)(hwb + (s0.w + lane4));
            g[4]  = *(const unsigned*)(hwb + (s1.x + lane4));
            g[5]  = *(const unsigned*)(hwb + (s1.y + lane4));
            g[6]  = *(const unsigned*)(hwb + (s1.z + lane4));
            g[7]  = *(const unsigned*)(hwb + (s1.w + lane4));
            g[8]  = *(const unsigned*)(hwb + (s2.x + lane4));
            g[9]  = *(const unsigned*)(hwb + (s2.y + lane4));
            g[10] = *(const unsigned*)(hwb + (s2.z + lane4));
            g[11] = *(const unsigned*)(hwb + (s2.w + lane4));
            g[12] = *(const unsigned*)(hwb + (s3.x + lane4));
            g[13] = *(const unsigned*)(hwb + (s3.y + lane4));
            g[14] = *(const unsigned*)(hwb + (s3.z + lane4));
            g[15] = *(const unsigned*)(hwb + (s3.w + lane4));
            ssum += (p0.x + p0.y + p0.z + p0.w) + (p1.x + p1.y + p1.z + p1.w)
                  + (p2.x + p2.y + p2.z + p2.w) + (p3.x + p3.y + p3.z + p3.w);
            const float p[16] = {p0.x, p0.y, p0.z, p0.w, p1.x, p1.y, p1.z, p1.w,
                                 p2.x, p2.y, p2.z, p2.w, p3.x, p3.y, p3.z, p3.w};
            #pragma unroll
            for (int j = 0; j < 16; ++j) {
                acc0 = fmaf(p[j], __uint_as_float((g[j] & 0xffffu) << 16), acc0);
                acc1 = fmaf(p[j], __uint_as_float(g[j] & 0xffff0000u), acc1);
            }
        }
        const float inv = 1.f / (ssum + 1e-16f);
        const float2 bv = *(const float2*)&bias[lane * 2];
        float2 o;
        o.x = fmaf(acc0, inv, bv.x);
        o.y = fmaf(acc1, inv, bv.y);
        *(float2*)&out[(size_t)node * CH + lane * 2] = o;
    }
}

extern "C" void kernel_launch(void* const* d_in, const int* in_sizes, int n_in,
                              void* d_out, int out_size, void* d_ws, size_t ws_size,
                              hipStream_t stream) {
    const float* x    = (const float*)d_in[0];
    const int*   ei   = (const int*)d_in[1];
    const float* W    = (const float*)d_in[2];
    const float* att  = (const float*)d_in[3];
    const float* bias = (const float*)d_in[4];
    float* out = (float*)d_out;

    const int N_   = in_sizes[0] / CH;   // 50000
    const int Etot = in_sizes[1] / 2;    // 850000
    const int* src = ei;
    const int* dst = ei + Etot;
    const int nb = (N_ + BNODES - 1) / BNODES;        // 1563
    const int gb = (N_ + 127) / 128;                  // 391 gemm blocks
    const int sb = (Etot + SCHUNK - 1) / SCHUNK;      // 208 scatter blocks

    char* ws = (char*)d_ws;
    size_t off = 0;
    auto alloc = [&](size_t bytes) -> void* {
        void* p = ws + off;
        off = (off + bytes + 255) & ~(size_t)255;
        return p;
    };
    unsigned short* hb = (unsigned short*)alloc((size_t)N_ * CH * sizeof(unsigned short));
    float* ad      = (float*)alloc((size_t)N_ * sizeof(float));
    float* as_     = (float*)alloc((size_t)N_ * sizeof(float));
    int*   gcur    = (int*)  alloc((size_t)nb * sizeof(int));
    unsigned* recs = (unsigned*)alloc((size_t)nb * CAP * sizeof(unsigned));
    (void)ws_size; (void)n_in; (void)out_size;

    hipMemsetAsync(gcur, 0, (size_t)nb * sizeof(int), stream);
    gemm_scatter_kernel<<<sb + gb, 256, 0, stream>>>(x, W, att, hb, ad, as_,
                                                     src, dst, gcur, recs, N_, Etot, nb, sb);
    aggregate_kernel<<<nb, 256, 0, stream>>>((const unsigned char*)hb, ad, as_, gcur, recs, bias, out, N_);
}